// Round 1
// baseline (1850.907 us; speedup 1.0000x reference)
//
#include <hip/hip_runtime.h>
#include <math.h>

// Problem constants (reference: N=8192, DIM=512, TOPK=10, all fp32)
#define NROWS 8192
#define DIMK  512
#define TOPK  10
#define STRIPS 4
#define STRIP_COLS (NROWS / STRIPS)   // 2048 columns per strip

// GEMM tiling: 64x64 C-tile per 256-thread block, 4x4 micro-tile/thread, TK=32.
#define TM 64
#define TN 64
#define TK 32
#define NTHREADS 256

// fp32(512**-0.5) — matches jax's python-double scale rounded to f32 at use.
#define SCALE 0.044194173824159223f

// ---------------------------------------------------------------------------
// Register-resident sorted top-k (ascending; vals[0] is the running minimum).
// Insert is an unrolled bubble pass — no dynamic register indexing (no spill).
// ---------------------------------------------------------------------------
__device__ __forceinline__ void topk_insert(float (&vals)[TOPK], int (&idxs)[TOPK],
                                            float v, int idx) {
  if (v > vals[0]) {
    vals[0] = v; idxs[0] = idx;
#pragma unroll
    for (int s = 0; s < TOPK - 1; ++s) {
      const bool sw = vals[s] > vals[s + 1];
      const float tv = vals[s]; const int ti = idxs[s];
      vals[s]     = sw ? vals[s + 1] : vals[s];
      idxs[s]     = sw ? idxs[s + 1] : idxs[s];
      vals[s + 1] = sw ? tv : vals[s + 1];
      idxs[s + 1] = sw ? ti : idxs[s + 1];
    }
  }
}

// ---------------------------------------------------------------------------
// Phase 1: E = X @ W^T + b for both Wh (cols 0..511 -> Eh) and Wt (-> Et).
// d-major LDS (As[d][row]) so the inner loop does b128 reads over contiguous
// rows/cols; A-fragment reads broadcast across the 16 tx lanes.
// ---------------------------------------------------------------------------
__global__ __launch_bounds__(NTHREADS, 4)
void embed_gemm(const float* __restrict__ X,
                const float* __restrict__ Wh, const float* __restrict__ bh,
                const float* __restrict__ Wt, const float* __restrict__ bt,
                float* __restrict__ Eh, float* __restrict__ Et) {
  __shared__ float As[TK][TM + 4];   // +4 keeps 16B alignment, spreads banks
  __shared__ float Bs[TK][TN + 4];

  const int tid = threadIdx.x;
  const int rowBase = blockIdx.x * TM;
  const int colBase = blockIdx.y * TN;          // 0..1023 over [Wh|Wt]
  const float* W  = (colBase < DIMK) ? Wh : Wt;
  const float* bb = (colBase < DIMK) ? bh : bt;
  float* Out      = (colBase < DIMK) ? Eh : Et;
  const int colOff = colBase & (DIMK - 1);

  const int tx = tid & 15, ty = tid >> 4;
  float acc[4][4];
#pragma unroll
  for (int r = 0; r < 4; ++r)
#pragma unroll
    for (int c = 0; c < 4; ++c) acc[r][c] = 0.f;

  for (int kt = 0; kt < DIMK; kt += TK) {
    __syncthreads();   // WAR: previous iteration's reads done before restage
#pragma unroll
    for (int u = 0; u < (TM * TK) / (4 * NTHREADS); ++u) {  // 2 float4 each
      const int idx = tid + u * NTHREADS;
      const int r = idx >> 3;      // 8 float4 per 32-wide d-slice
      const int dc = idx & 7;
      const float4 av = *(const float4*)&X[(size_t)(rowBase + r) * DIMK + kt + dc * 4];
      As[dc * 4 + 0][r] = av.x; As[dc * 4 + 1][r] = av.y;
      As[dc * 4 + 2][r] = av.z; As[dc * 4 + 3][r] = av.w;
      const float4 bv = *(const float4*)&W[(size_t)(colOff + r) * DIMK + kt + dc * 4];
      Bs[dc * 4 + 0][r] = bv.x; Bs[dc * 4 + 1][r] = bv.y;
      Bs[dc * 4 + 2][r] = bv.z; Bs[dc * 4 + 3][r] = bv.w;
    }
    __syncthreads();
#pragma unroll
    for (int d4 = 0; d4 < TK; d4 += 4) {
#pragma unroll
      for (int q = 0; q < 4; ++q) {
        const float4 a = *(const float4*)&As[d4 + q][ty * 4];
        const float4 b = *(const float4*)&Bs[d4 + q][tx * 4];
        const float ar[4] = {a.x, a.y, a.z, a.w};
        const float br[4] = {b.x, b.y, b.z, b.w};
#pragma unroll
        for (int r = 0; r < 4; ++r)
#pragma unroll
          for (int c = 0; c < 4; ++c)
            acc[r][c] = fmaf(ar[r], br[c], acc[r][c]);
      }
    }
  }

  const float4 bv = *(const float4*)&bb[colOff + tx * 4];
  const float br[4] = {bv.x, bv.y, bv.z, bv.w};
#pragma unroll
  for (int r = 0; r < 4; ++r) {
    float4 o;
    o.x = acc[r][0] + br[0]; o.y = acc[r][1] + br[1];
    o.z = acc[r][2] + br[2]; o.w = acc[r][3] + br[3];
    *(float4*)&Out[(size_t)(rowBase + ty * 4 + r) * DIMK + colOff + tx * 4] = o;
  }
}

// ---------------------------------------------------------------------------
// Phase 2: fused logits tile GEMM + per-row running top-10.
// Block = 64 rows x one 2048-col strip. Per 64-col tile: GEMM in registers,
// dump scaled tile to LDS, then 4 threads/row scan 16 cols each into a
// register top-10. Partials (4 strips x 4 col-groups per row) go to ws.
// ---------------------------------------------------------------------------
__global__ __launch_bounds__(NTHREADS, 4)
void logits_topk(const float* __restrict__ Eh, const float* __restrict__ Et,
                 float* __restrict__ pval, int* __restrict__ pidx) {
  __shared__ float As[TK][TM + 4];
  __shared__ float Bs[TK][TN + 4];
  __shared__ float Cs[TM][TN + 1];   // +1: scan reads are conflict-free

  const int tid = threadIdx.x;
  const int rowBase = blockIdx.x * TM;
  const int strip = blockIdx.y;
  const int stripBase = strip * STRIP_COLS;
  const int tx = tid & 15, ty = tid >> 4;
  const int srow = tid & 63, scg = tid >> 6;

  float vals[TOPK]; int idxs[TOPK];
#pragma unroll
  for (int s = 0; s < TOPK; ++s) { vals[s] = -INFINITY; idxs[s] = 0; }

  for (int ct = 0; ct < STRIP_COLS; ct += TN) {
    const int colBase = stripBase + ct;
    float acc[4][4];
#pragma unroll
    for (int r = 0; r < 4; ++r)
#pragma unroll
      for (int c = 0; c < 4; ++c) acc[r][c] = 0.f;

    for (int kt = 0; kt < DIMK; kt += TK) {
      __syncthreads();  // also separates previous tile's Cs scan from restage
#pragma unroll
      for (int u = 0; u < (TM * TK) / (4 * NTHREADS); ++u) {
        const int idx = tid + u * NTHREADS;
        const int r = idx >> 3;
        const int dc = idx & 7;
        const float4 av = *(const float4*)&Eh[(size_t)(rowBase + r) * DIMK + kt + dc * 4];
        As[dc * 4 + 0][r] = av.x; As[dc * 4 + 1][r] = av.y;
        As[dc * 4 + 2][r] = av.z; As[dc * 4 + 3][r] = av.w;
        const float4 bv = *(const float4*)&Et[(size_t)(colBase + r) * DIMK + kt + dc * 4];
        Bs[dc * 4 + 0][r] = bv.x; Bs[dc * 4 + 1][r] = bv.y;
        Bs[dc * 4 + 2][r] = bv.z; Bs[dc * 4 + 3][r] = bv.w;
      }
      __syncthreads();
#pragma unroll
      for (int d4 = 0; d4 < TK; d4 += 4) {
#pragma unroll
        for (int q = 0; q < 4; ++q) {
          const float4 a = *(const float4*)&As[d4 + q][ty * 4];
          const float4 b = *(const float4*)&Bs[d4 + q][tx * 4];
          const float ar[4] = {a.x, a.y, a.z, a.w};
          const float br[4] = {b.x, b.y, b.z, b.w};
#pragma unroll
          for (int r = 0; r < 4; ++r)
#pragma unroll
            for (int c = 0; c < 4; ++c)
              acc[r][c] = fmaf(ar[r], br[c], acc[r][c]);
        }
      }
    }

    // Dump scaled tile; scan it row-per-thread-quarter into register top-10.
#pragma unroll
    for (int r = 0; r < 4; ++r)
#pragma unroll
      for (int c = 0; c < 4; ++c)
        Cs[ty * 4 + r][tx * 4 + c] = acc[r][c] * SCALE;
    __syncthreads();
#pragma unroll
    for (int i = 0; i < 16; ++i) {
      const float v = Cs[srow][scg * 16 + i];
      topk_insert(vals, idxs, v, colBase + scg * 16 + i);
    }
    // next iteration's first __syncthreads() separates scan from Cs re-dump
  }

  const size_t base = (((size_t)strip * NROWS + rowBase + srow) * 4 + scg) * TOPK;
#pragma unroll
  for (int s = 0; s < TOPK; ++s) { pval[base + s] = vals[s]; pidx[base + s] = idxs[s]; }
}

// ---------------------------------------------------------------------------
// Phase 3: merge 16 partial top-10s per row, softmax, emit edge list.
// Output layout (all fp32): [src (N*K)] [dst (N*K)] [weight (N*K)].
// ---------------------------------------------------------------------------
__global__ __launch_bounds__(NTHREADS)
void merge_topk(const float* __restrict__ pval, const int* __restrict__ pidx,
                float* __restrict__ out) {
  const int r = blockIdx.x * blockDim.x + threadIdx.x;
  if (r >= NROWS) return;
  float vals[TOPK]; int idxs[TOPK];
#pragma unroll
  for (int s = 0; s < TOPK; ++s) { vals[s] = -INFINITY; idxs[s] = 0; }

  for (int strip = 0; strip < STRIPS; ++strip) {
    for (int cg = 0; cg < 4; ++cg) {
      const size_t base = (((size_t)strip * NROWS + r) * 4 + cg) * TOPK;
#pragma unroll
      for (int s = 0; s < TOPK; ++s)
        topk_insert(vals, idxs, pval[base + s], pidx[base + s]);
    }
  }

  // vals ascending -> emit descending (matches jax.lax.top_k order)
  const float m = vals[TOPK - 1];
  float w[TOPK]; float sum = 0.f;
#pragma unroll
  for (int j = 0; j < TOPK; ++j) { w[j] = expf(vals[TOPK - 1 - j] - m); sum += w[j]; }
  const float inv = 1.0f / sum;

  const size_t ro = (size_t)r * TOPK;
#pragma unroll
  for (int j = 0; j < TOPK; ++j) {
    out[ro + j] = (float)r;                                       // src
    out[(size_t)NROWS * TOPK + ro + j] = (float)idxs[TOPK - 1 - j]; // dst
    out[2 * (size_t)NROWS * TOPK + ro + j] = w[j] * inv;          // weight
  }
}

// ---------------------------------------------------------------------------
extern "C" void kernel_launch(void* const* d_in, const int* in_sizes, int n_in,
                              void* d_out, int out_size, void* d_ws, size_t ws_size,
                              hipStream_t stream) {
  const float* X  = (const float*)d_in[0];
  const float* Wh = (const float*)d_in[1];
  const float* bh = (const float*)d_in[2];
  const float* Wt = (const float*)d_in[3];
  const float* bt = (const float*)d_in[4];
  float* out = (float*)d_out;

  char* ws = (char*)d_ws;
  const size_t embBytes = (size_t)NROWS * DIMK * sizeof(float);       // 16 MB
  float* Eh = (float*)ws;
  float* Et = (float*)(ws + embBytes);
  const size_t partElems = (size_t)STRIPS * NROWS * 4 * TOPK;         // 1.31M
  float* pval = (float*)(ws + 2 * embBytes);
  int*   pidx = (int*)(ws + 2 * embBytes + partElems * sizeof(float));
  // total ws use: 32 MB + ~10.5 MB

  dim3 blk(NTHREADS);
  dim3 g1(NROWS / TM, (2 * DIMK) / TN);        // 128 x 16
  embed_gemm<<<g1, blk, 0, stream>>>(X, Wh, bh, Wt, bt, Eh, Et);

  dim3 g2(NROWS / TM, STRIPS);                 // 128 x 4
  logits_topk<<<g2, blk, 0, stream>>>(Eh, Et, pval, pidx);

  merge_topk<<<NROWS / NTHREADS, blk, 0, stream>>>(pval, pidx, out);
}

// Round 3
// 609.260 us; speedup vs baseline: 3.0380x; 3.0380x over previous
//
#include <hip/hip_runtime.h>
#include <math.h>

// Problem constants (reference: N=8192, DIM=512, TOPK=10, all fp32)
#define NROWS 8192
#define DIMK  512
#define TOPK  10
#define SCALE 0.044194173824159223f   // fp32(512**-0.5)

// Phase-1 embed GEMM tiling (fp32 VALU)
#define TM 64
#define TN 64
#define TK 32
#define NTHREADS 256

// Phase-2 screen GEMM tiling (bf16 MFMA)
#define BM 128
#define BN 128
#define BK 32
#define NS 8                    // column strips
#define SCOLS (NROWS / NS)      // 1024 cols per strip
#define CAND 16                 // rescored candidates per row

typedef __attribute__((ext_vector_type(8))) short bf16x8;   // 8 bf16 = 4 VGPRs
typedef __attribute__((ext_vector_type(4))) float f32x4;

// ---------------------------------------------------------------------------
// Register-resident sorted top-K (ascending; vals[0] = running min).
// ---------------------------------------------------------------------------
template <int K>
__device__ __forceinline__ void tk_insert(float (&vals)[K], int (&idxs)[K],
                                          float v, int idx) {
  if (v > vals[0]) {
    vals[0] = v; idxs[0] = idx;
#pragma unroll
    for (int s = 0; s < K - 1; ++s) {
      const bool sw = vals[s] > vals[s + 1];
      const float tv = vals[s]; const int ti = idxs[s];
      vals[s]     = sw ? vals[s + 1] : vals[s];
      idxs[s]     = sw ? idxs[s + 1] : idxs[s];
      vals[s + 1] = sw ? tv : vals[s + 1];
      idxs[s + 1] = sw ? ti : idxs[s + 1];
    }
  }
}

__device__ __forceinline__ unsigned short f2bf(float f) {   // RNE fp32->bf16
  unsigned int u = __float_as_uint(f);
  u = (u + 0x7FFF + ((u >> 16) & 1)) >> 16;
  return (unsigned short)u;
}

// async global->LDS, 16B per lane; lds ptr must be wave-uniform base
__device__ __forceinline__ void gld16(const void* g, const void* lds) {
  __builtin_amdgcn_global_load_lds(
      (const __attribute__((address_space(1))) void*)g,
      (__attribute__((address_space(3))) void*)lds, 16, 0, 0);
}

// ---------------------------------------------------------------------------
// Phase 1: E = X @ W^T + b (fp32 exact, feeds rescore) + bf16 copies (screen).
// ---------------------------------------------------------------------------
__global__ __launch_bounds__(NTHREADS, 4)
void embed_gemm(const float* __restrict__ X,
                const float* __restrict__ Wh, const float* __restrict__ bh,
                const float* __restrict__ Wt, const float* __restrict__ bt,
                float* __restrict__ Eh, float* __restrict__ Et,
                unsigned short* __restrict__ Ehb, unsigned short* __restrict__ Etb) {
  __shared__ float As[TK][TM + 4];
  __shared__ float Bs[TK][TN + 4];

  const int tid = threadIdx.x;
  const int rowBase = blockIdx.x * TM;
  const int colBase = blockIdx.y * TN;          // 0..1023 over [Wh|Wt]
  const float* W  = (colBase < DIMK) ? Wh : Wt;
  const float* bb = (colBase < DIMK) ? bh : bt;
  float* Out            = (colBase < DIMK) ? Eh : Et;
  unsigned short* Outb  = (colBase < DIMK) ? Ehb : Etb;
  const int colOff = colBase & (DIMK - 1);

  const int tx = tid & 15, ty = tid >> 4;
  float acc[4][4];
#pragma unroll
  for (int r = 0; r < 4; ++r)
#pragma unroll
    for (int c = 0; c < 4; ++c) acc[r][c] = 0.f;

  for (int kt = 0; kt < DIMK; kt += TK) {
    __syncthreads();
#pragma unroll
    for (int u = 0; u < (TM * TK) / (4 * NTHREADS); ++u) {
      const int idx = tid + u * NTHREADS;
      const int r = idx >> 3;
      const int dc = idx & 7;
      const float4 av = *(const float4*)&X[(size_t)(rowBase + r) * DIMK + kt + dc * 4];
      As[dc * 4 + 0][r] = av.x; As[dc * 4 + 1][r] = av.y;
      As[dc * 4 + 2][r] = av.z; As[dc * 4 + 3][r] = av.w;
      const float4 bv = *(const float4*)&W[(size_t)(colOff + r) * DIMK + kt + dc * 4];
      Bs[dc * 4 + 0][r] = bv.x; Bs[dc * 4 + 1][r] = bv.y;
      Bs[dc * 4 + 2][r] = bv.z; Bs[dc * 4 + 3][r] = bv.w;
    }
    __syncthreads();
#pragma unroll
    for (int d4 = 0; d4 < TK; d4 += 4) {
#pragma unroll
      for (int q = 0; q < 4; ++q) {
        const float4 a = *(const float4*)&As[d4 + q][ty * 4];
        const float4 b = *(const float4*)&Bs[d4 + q][tx * 4];
        const float ar[4] = {a.x, a.y, a.z, a.w};
        const float br[4] = {b.x, b.y, b.z, b.w};
#pragma unroll
        for (int r = 0; r < 4; ++r)
#pragma unroll
          for (int c = 0; c < 4; ++c)
            acc[r][c] = fmaf(ar[r], br[c], acc[r][c]);
      }
    }
  }

  const float4 bv = *(const float4*)&bb[colOff + tx * 4];
  const float br[4] = {bv.x, bv.y, bv.z, bv.w};
#pragma unroll
  for (int r = 0; r < 4; ++r) {
    float4 o;
    o.x = acc[r][0] + br[0]; o.y = acc[r][1] + br[1];
    o.z = acc[r][2] + br[2]; o.w = acc[r][3] + br[3];
    const size_t off = (size_t)(rowBase + ty * 4 + r) * DIMK + colOff + tx * 4;
    *(float4*)&Out[off] = o;
    ushort4 ob;
    ob.x = f2bf(o.x); ob.y = f2bf(o.y); ob.z = f2bf(o.z); ob.w = f2bf(o.w);
    *(ushort4*)&Outb[off] = ob;
  }
}

// ---------------------------------------------------------------------------
// Phase 2: bf16 MFMA screening GEMM (ranking only) + fused per-row top-10
// into 2 disjoint column buckets per (row, strip). Block = 128 rows x one
// 1024-col strip; 4 waves, 64x64 subtile/wave.
// ---------------------------------------------------------------------------
__global__ __launch_bounds__(256, 2)
void screen_topk(const unsigned short* __restrict__ Ehb,
                 const unsigned short* __restrict__ Etb,
                 float* __restrict__ pval, int* __restrict__ pidx) {
  __shared__ unsigned short As[BM * BK];   // 8 KB, row-major [128][32]
  __shared__ unsigned short Bs[BN * BK];   // 8 KB
  __shared__ float Cs[BM][66];             // 33.8 KB

  const int tid = threadIdx.x;
  const int rowBase = blockIdx.x * BM;
  const int strip = blockIdx.y;
  const int w = tid >> 6, lane = tid & 63;
  const int q = lane >> 4, l15 = lane & 15;
  const int wr = (w & 1) * 64, wc = (w >> 1) * 64;   // wave subtile origin
  const int srow = tid & 127, sg = tid >> 7;          // scan row / col-group

  // staging chunks: 512 x 16B per 8KB tile; thread stages chunk tid, tid+256
  const int c0 = tid, c1 = tid + 256;
  const int wb0 = __builtin_amdgcn_readfirstlane(tid & ~63);  // wave chunk base
  const int wb1 = wb0 + 256;
  const int ar0 = c0 >> 2, ac0 = (c0 & 3) * 8;
  const int ar1 = c1 >> 2, ac1 = (c1 & 3) * 8;

  float vals[TOPK]; int idxs[TOPK];
#pragma unroll
  for (int s = 0; s < TOPK; ++s) { vals[s] = -INFINITY; idxs[s] = 0; }

  for (int ct = 0; ct < SCOLS; ct += BN) {
    const int colBase = strip * SCOLS + ct;
    f32x4 acc[4][4];
#pragma unroll
    for (int i = 0; i < 4; ++i)
#pragma unroll
      for (int j = 0; j < 4; ++j) acc[i][j] = (f32x4){0.f, 0.f, 0.f, 0.f};

    for (int kt = 0; kt < DIMK; kt += BK) {
      __syncthreads();
      gld16(Ehb + (size_t)(rowBase + ar0) * DIMK + kt + ac0, As + wb0 * 8);
      gld16(Ehb + (size_t)(rowBase + ar1) * DIMK + kt + ac1, As + wb1 * 8);
      gld16(Etb + (size_t)(colBase + ar0) * DIMK + kt + ac0, Bs + wb0 * 8);
      gld16(Etb + (size_t)(colBase + ar1) * DIMK + kt + ac1, Bs + wb1 * 8);
      __syncthreads();   // drains vmcnt (global_load_lds) + orders LDS

      bf16x8 af[4], bf[4];
#pragma unroll
      for (int i = 0; i < 4; ++i)
        af[i] = *(const bf16x8*)&As[(wr + i * 16 + l15) * BK + q * 8];
#pragma unroll
      for (int j = 0; j < 4; ++j)
        bf[j] = *(const bf16x8*)&Bs[(wc + j * 16 + l15) * BK + q * 8];
#pragma unroll
      for (int i = 0; i < 4; ++i)
#pragma unroll
        for (int j = 0; j < 4; ++j)
          acc[i][j] = __builtin_amdgcn_mfma_f32_16x16x32_bf16(af[i], bf[j], acc[i][j], 0, 0, 0);
    }

    // Dump+scan in two 64-col halves (Cs used as 128x64).
    for (int half = 0; half < 2; ++half) {
      if ((w >> 1) == half) {
#pragma unroll
        for (int i = 0; i < 4; ++i)
#pragma unroll
          for (int j = 0; j < 4; ++j)
#pragma unroll
          for (int rg = 0; rg < 4; ++rg)
            Cs[wr + i * 16 + q * 4 + rg][j * 16 + l15] = acc[i][j][rg];
      }
      __syncthreads();
#pragma unroll
      for (int i = 0; i < 32; ++i) {
        const float v = Cs[srow][sg * 32 + i];
        tk_insert<TOPK>(vals, idxs, v, colBase + half * 64 + sg * 32 + i);
      }
      __syncthreads();   // scan done before next dump overwrites Cs
    }
  }

  const size_t base = (((size_t)(rowBase + srow) * NS + strip) * 2 + sg) * TOPK;
#pragma unroll
  for (int s = 0; s < TOPK; ++s) { pval[base + s] = vals[s]; pidx[base + s] = idxs[s]; }
}

// ---------------------------------------------------------------------------
// Phase 3a: merge 16 bucket top-10s per row -> top-16 candidate columns.
// ---------------------------------------------------------------------------
__global__ __launch_bounds__(256)
void merge16(const float* __restrict__ pval, const int* __restrict__ pidx,
             int* __restrict__ cand) {
  const int r = blockIdx.x * 256 + threadIdx.x;
  float v[CAND]; int id[CAND];
#pragma unroll
  for (int s = 0; s < CAND; ++s) { v[s] = -INFINITY; id[s] = 0; }
  const size_t base = (size_t)r * (NS * 2 * TOPK);
  for (int c = 0; c < NS * 2 * TOPK; ++c)
    tk_insert<CAND>(v, id, pval[base + c], pidx[base + c]);
#pragma unroll
  for (int s = 0; s < CAND; ++s) cand[(size_t)r * CAND + s] = id[s];
}

// ---------------------------------------------------------------------------
// Phase 3b: rescore candidates with arithmetic BIT-IDENTICAL to round-1's
// logits path: p = sequential fmaf chain over k=0..511, then v = p*SCALE.
// One thread per (row, candidate). (Do NOT tree-reduce: a different fp32
// summation order flipped a rank-10/11 near-tie vs the numpy reference.)
// ---------------------------------------------------------------------------
__global__ __launch_bounds__(256)
void rescore_chain(const float* __restrict__ Eh, const float* __restrict__ Et,
                   const int* __restrict__ cand, float* __restrict__ pscore) {
  const int idx = blockIdx.x * 256 + threadIdx.x;     // [0, NROWS*CAND)
  const int r = idx >> 4, c = idx & 15;
  const int cc = cand[(size_t)r * CAND + c];
  const float* a = Eh + (size_t)r * DIMK;
  const float* b = Et + (size_t)cc * DIMK;
  float p = 0.f;
#pragma unroll 4
  for (int k = 0; k < DIMK; k += 4) {
    const float4 av = *(const float4*)&a[k];
    const float4 bv = *(const float4*)&b[k];
    p = fmaf(av.x, bv.x, p);
    p = fmaf(av.y, bv.y, p);
    p = fmaf(av.z, bv.z, p);
    p = fmaf(av.w, bv.w, p);
  }
  pscore[idx] = p * SCALE;   // scale AFTER chain, as round 1 did
}

// ---------------------------------------------------------------------------
// Phase 3c: top-10 of the 16 exact scores, softmax, emit edge list.
// Output layout (all fp32): [src N*K][dst N*K][weight N*K].
// ---------------------------------------------------------------------------
__global__ __launch_bounds__(256)
void finalize(const float* __restrict__ pscore, const int* __restrict__ cand,
              float* __restrict__ out) {
  const int r = blockIdx.x * 256 + threadIdx.x;
  float vals[TOPK]; int idxs[TOPK];
#pragma unroll
  for (int s = 0; s < TOPK; ++s) { vals[s] = -INFINITY; idxs[s] = 0; }
#pragma unroll
  for (int c = 0; c < CAND; ++c)
    tk_insert<TOPK>(vals, idxs, pscore[(size_t)r * CAND + c],
                    cand[(size_t)r * CAND + c]);

  // vals ascending -> emit descending (matches jax.lax.top_k order)
  const float m = vals[TOPK - 1];
  float w[TOPK]; float sum = 0.f;
#pragma unroll
  for (int j = 0; j < TOPK; ++j) { w[j] = expf(vals[TOPK - 1 - j] - m); sum += w[j]; }
  const float inv = 1.0f / sum;

  const size_t ro = (size_t)r * TOPK;
#pragma unroll
  for (int j = 0; j < TOPK; ++j) {
    out[ro + j] = (float)r;                                         // src
    out[(size_t)NROWS * TOPK + ro + j] = (float)idxs[TOPK - 1 - j]; // dst
    out[2 * (size_t)NROWS * TOPK + ro + j] = w[j] * inv;            // weight
  }
}

// ---------------------------------------------------------------------------
extern "C" void kernel_launch(void* const* d_in, const int* in_sizes, int n_in,
                              void* d_out, int out_size, void* d_ws, size_t ws_size,
                              hipStream_t stream) {
  const float* X  = (const float*)d_in[0];
  const float* Wh = (const float*)d_in[1];
  const float* bh = (const float*)d_in[2];
  const float* Wt = (const float*)d_in[3];
  const float* bt = (const float*)d_in[4];
  float* out = (float*)d_out;

  char* ws = (char*)d_ws;
  const size_t embB  = (size_t)NROWS * DIMK * sizeof(float);          // 16 MB
  const size_t embBH = (size_t)NROWS * DIMK * sizeof(unsigned short); //  8 MB
  const size_t partB = (size_t)NS * 2 * TOPK * NROWS * sizeof(float); // 5.24 MB
  const size_t candB = (size_t)NROWS * CAND * sizeof(int);            // 0.5 MB
  float* Eh = (float*)ws;
  float* Et = (float*)(ws + embB);
  unsigned short* Ehb = (unsigned short*)(ws + 2 * embB);
  unsigned short* Etb = (unsigned short*)(ws + 2 * embB + embBH);
  float* pval = (float*)(ws + 2 * embB + 2 * embBH);
  int*   pidx = (int*)(ws + 2 * embB + 2 * embBH + partB);
  int*   cand = (int*)(ws + 2 * embB + 2 * embBH + 2 * partB);
  float* pscore = (float*)(ws + 2 * embB + 2 * embBH + 2 * partB + candB);
  // total ws use ~59.5 MB

  dim3 blk(NTHREADS);
  dim3 g1(NROWS / TM, (2 * DIMK) / TN);        // 128 x 16
  embed_gemm<<<g1, blk, 0, stream>>>(X, Wh, bh, Wt, bt, Eh, Et, Ehb, Etb);

  dim3 g2(NROWS / BM, NS);                     // 64 x 8
  screen_topk<<<g2, blk, 0, stream>>>(Ehb, Etb, pval, pidx);

  merge16<<<NROWS / 256, blk, 0, stream>>>(pval, pidx, cand);

  rescore_chain<<<(NROWS * CAND) / 256, blk, 0, stream>>>(Eh, Et, cand, pscore);

  finalize<<<NROWS / 256, blk, 0, stream>>>(pscore, cand, out);
}

// Round 4
// 557.846 us; speedup vs baseline: 3.3180x; 1.0922x over previous
//
#include <hip/hip_runtime.h>
#include <math.h>

// Problem constants (reference: N=8192, DIM=512, TOPK=10, all fp32)
#define NROWS 8192
#define DIMK  512
#define TOPK  10
#define SCALE 0.044194173824159223f   // fp32(512**-0.5)

// Phase-1 embed GEMM tiling (fp32 VALU)
#define TM 64
#define TN 64
#define TK 32
#define NTHREADS 256

// Screen GEMM tiling (bf16 MFMA)
#define BM 128
#define BN 128
#define BK 32
#define NS2 16                    // column strips for screen passes
#define SCOLS2 (NROWS / NS2)      // 512 cols per strip (4 tiles)
#define NQ 256                    // 32-col quarter-groups per row (8192/32)
#define CAP 64                    // max candidates per row
#define TMARGIN 2.0f              // threshold safety margin (~11 sigma of bf16 noise)

typedef __attribute__((ext_vector_type(8))) short bf16x8;   // 8 bf16 = 4 VGPRs
typedef __attribute__((ext_vector_type(4))) float f32x4;

// ---------------------------------------------------------------------------
// Register-resident sorted top-K (ascending; vals[0] = running min).
// ---------------------------------------------------------------------------
template <int K>
__device__ __forceinline__ void tk_insert(float (&vals)[K], int (&idxs)[K],
                                          float v, int idx) {
  if (v > vals[0]) {
    vals[0] = v; idxs[0] = idx;
#pragma unroll
    for (int s = 0; s < K - 1; ++s) {
      const bool sw = vals[s] > vals[s + 1];
      const float tv = vals[s]; const int ti = idxs[s];
      vals[s]     = sw ? vals[s + 1] : vals[s];
      idxs[s]     = sw ? idxs[s + 1] : idxs[s];
      vals[s + 1] = sw ? tv : vals[s + 1];
      idxs[s + 1] = sw ? ti : idxs[s + 1];
    }
  }
}

// values-only variant (for threshold computation)
template <int K>
__device__ __forceinline__ void tkv_insert(float (&vals)[K], float v) {
  if (v > vals[0]) {
    vals[0] = v;
#pragma unroll
    for (int s = 0; s < K - 1; ++s) {
      const bool sw = vals[s] > vals[s + 1];
      const float tv = vals[s];
      vals[s]     = sw ? vals[s + 1] : vals[s];
      vals[s + 1] = sw ? tv : vals[s + 1];
    }
  }
}

__device__ __forceinline__ unsigned short f2bf(float f) {   // RNE fp32->bf16
  unsigned int u = __float_as_uint(f);
  u = (u + 0x7FFF + ((u >> 16) & 1)) >> 16;
  return (unsigned short)u;
}

// async global->LDS, 16B per lane; lds ptr must be wave-uniform base
__device__ __forceinline__ void gld16(const void* g, const void* lds) {
  __builtin_amdgcn_global_load_lds(
      (const __attribute__((address_space(1))) void*)g,
      (__attribute__((address_space(3))) void*)lds, 16, 0, 0);
}

// ---------------------------------------------------------------------------
// Phase 1: E = X @ W^T + b (fp32 exact, feeds rescore) + bf16 copies (screen).
// Arithmetic must stay bit-identical across rounds (rank near-ties).
// ---------------------------------------------------------------------------
__global__ __launch_bounds__(NTHREADS, 4)
void embed_gemm(const float* __restrict__ X,
                const float* __restrict__ Wh, const float* __restrict__ bh,
                const float* __restrict__ Wt, const float* __restrict__ bt,
                float* __restrict__ Eh, float* __restrict__ Et,
                unsigned short* __restrict__ Ehb, unsigned short* __restrict__ Etb) {
  __shared__ float As[TK][TM + 4];
  __shared__ float Bs[TK][TN + 4];

  const int tid = threadIdx.x;
  const int rowBase = blockIdx.x * TM;
  const int colBase = blockIdx.y * TN;          // 0..1023 over [Wh|Wt]
  const float* W  = (colBase < DIMK) ? Wh : Wt;
  const float* bb = (colBase < DIMK) ? bh : bt;
  float* Out            = (colBase < DIMK) ? Eh : Et;
  unsigned short* Outb  = (colBase < DIMK) ? Ehb : Etb;
  const int colOff = colBase & (DIMK - 1);

  const int tx = tid & 15, ty = tid >> 4;
  float acc[4][4];
#pragma unroll
  for (int r = 0; r < 4; ++r)
#pragma unroll
    for (int c = 0; c < 4; ++c) acc[r][c] = 0.f;

  for (int kt = 0; kt < DIMK; kt += TK) {
    __syncthreads();
#pragma unroll
    for (int u = 0; u < (TM * TK) / (4 * NTHREADS); ++u) {
      const int idx = tid + u * NTHREADS;
      const int r = idx >> 3;
      const int dc = idx & 7;
      const float4 av = *(const float4*)&X[(size_t)(rowBase + r) * DIMK + kt + dc * 4];
      As[dc * 4 + 0][r] = av.x; As[dc * 4 + 1][r] = av.y;
      As[dc * 4 + 2][r] = av.z; As[dc * 4 + 3][r] = av.w;
      const float4 bv = *(const float4*)&W[(size_t)(colOff + r) * DIMK + kt + dc * 4];
      Bs[dc * 4 + 0][r] = bv.x; Bs[dc * 4 + 1][r] = bv.y;
      Bs[dc * 4 + 2][r] = bv.z; Bs[dc * 4 + 3][r] = bv.w;
    }
    __syncthreads();
#pragma unroll
    for (int d4 = 0; d4 < TK; d4 += 4) {
#pragma unroll
      for (int q = 0; q < 4; ++q) {
        const float4 a = *(const float4*)&As[d4 + q][ty * 4];
        const float4 b = *(const float4*)&Bs[d4 + q][tx * 4];
        const float ar[4] = {a.x, a.y, a.z, a.w};
        const float br[4] = {b.x, b.y, b.z, b.w};
#pragma unroll
        for (int r = 0; r < 4; ++r)
#pragma unroll
          for (int c = 0; c < 4; ++c)
            acc[r][c] = fmaf(ar[r], br[c], acc[r][c]);
      }
    }
  }

  const float4 bv = *(const float4*)&bb[colOff + tx * 4];
  const float br[4] = {bv.x, bv.y, bv.z, bv.w};
#pragma unroll
  for (int r = 0; r < 4; ++r) {
    float4 o;
    o.x = acc[r][0] + br[0]; o.y = acc[r][1] + br[1];
    o.z = acc[r][2] + br[2]; o.w = acc[r][3] + br[3];
    const size_t off = (size_t)(rowBase + ty * 4 + r) * DIMK + colOff + tx * 4;
    *(float4*)&Out[off] = o;
    ushort4 ob;
    ob.x = f2bf(o.x); ob.y = f2bf(o.y); ob.z = f2bf(o.z); ob.w = f2bf(o.w);
    *(ushort4*)&Outb[off] = ob;
  }
}

// ---------------------------------------------------------------------------
// Screen pass A: bf16 MFMA GEMM; epilogue emits per-row maxes of each 32-col
// group via an LDS roundtrip (pad 68 -> only free 2-way conflicts).
// Block = 128 rows x 512-col strip (4 tiles); 4 waves, 64x64 subtile each.
// ---------------------------------------------------------------------------
__global__ __launch_bounds__(256, 3)
void screen_max(const unsigned short* __restrict__ Ehb,
                const unsigned short* __restrict__ Etb,
                float* __restrict__ tmax) {
  __shared__ unsigned short As[BM * BK];   // 8 KB
  __shared__ unsigned short Bs[BN * BK];   // 8 KB
  __shared__ float Cs[BM][68];             // 34.8 KB; stride 68: 16B-aligned rows

  const int tid = threadIdx.x;
  const int rowBase = blockIdx.x * BM;
  const int strip = blockIdx.y;
  const int w = tid >> 6, lane = tid & 63;
  const int q = lane >> 4, l15 = lane & 15;
  const int wr = (w & 1) * 64, wc = (w >> 1) * 64;
  const int rr = tid & 127, hq = tid >> 7;   // readback row / 32-col quarter

  const int c0 = tid, c1 = tid + 256;
  const int wb0 = __builtin_amdgcn_readfirstlane(tid & ~63);
  const int wb1 = wb0 + 256;
  const int ar0 = c0 >> 2, ac0 = (c0 & 3) * 8;
  const int ar1 = c1 >> 2, ac1 = (c1 & 3) * 8;

  for (int ct = 0; ct < SCOLS2; ct += BN) {
    const int colBase = strip * SCOLS2 + ct;
    const int tileG = colBase >> 7;          // global 128-col tile index
    f32x4 acc[4][4];
#pragma unroll
    for (int i = 0; i < 4; ++i)
#pragma unroll
      for (int j = 0; j < 4; ++j) acc[i][j] = (f32x4){0.f, 0.f, 0.f, 0.f};

    for (int kt = 0; kt < DIMK; kt += BK) {
      __syncthreads();
      gld16(Ehb + (size_t)(rowBase + ar0) * DIMK + kt + ac0, As + wb0 * 8);
      gld16(Ehb + (size_t)(rowBase + ar1) * DIMK + kt + ac1, As + wb1 * 8);
      gld16(Etb + (size_t)(colBase + ar0) * DIMK + kt + ac0, Bs + wb0 * 8);
      gld16(Etb + (size_t)(colBase + ar1) * DIMK + kt + ac1, Bs + wb1 * 8);
      __syncthreads();

      bf16x8 af[4], bf[4];
#pragma unroll
      for (int i = 0; i < 4; ++i)
        af[i] = *(const bf16x8*)&As[(wr + i * 16 + l15) * BK + q * 8];
#pragma unroll
      for (int j = 0; j < 4; ++j)
        bf[j] = *(const bf16x8*)&Bs[(wc + j * 16 + l15) * BK + q * 8];
#pragma unroll
      for (int i = 0; i < 4; ++i)
#pragma unroll
        for (int j = 0; j < 4; ++j)
          acc[i][j] = __builtin_amdgcn_mfma_f32_16x16x32_bf16(af[i], bf[j], acc[i][j], 0, 0, 0);
    }

    // Epilogue: per 64-col half, dump + row-contiguous readback -> group max.
#pragma unroll
    for (int half = 0; half < 2; ++half) {
      if ((w >> 1) == half) {
#pragma unroll
        for (int i = 0; i < 4; ++i)
#pragma unroll
          for (int j = 0; j < 4; ++j)
#pragma unroll
            for (int rg = 0; rg < 4; ++rg)
              Cs[wr + i * 16 + q * 4 + rg][j * 16 + l15] = acc[i][j][rg];
      }
      __syncthreads();
      float m = -INFINITY;
#pragma unroll
      for (int k = 0; k < 8; ++k) {
        const f32x4 v = *(const f32x4*)&Cs[rr][hq * 32 + k * 4];
        m = fmaxf(m, fmaxf(fmaxf(v[0], v[1]), fmaxf(v[2], v[3])));
      }
      tmax[(size_t)(rowBase + rr) * NQ + tileG * 4 + half * 2 + hq] = m;
      __syncthreads();   // readback done before next dump overwrites Cs
    }
  }
}

// ---------------------------------------------------------------------------
// Threshold: t[row] = (10th-best of 256 group maxes) - TMARGIN; zero cnt.
// >=10 disjoint groups have max >= 10th-best => >=10 cols >= t+TMARGIN,
// so every fp32-top-10 col clears t with ~11 sigma of bf16-noise margin.
// Block = 64 rows x 4 parts.
// ---------------------------------------------------------------------------
__global__ __launch_bounds__(256)
void row_thresh(const float* __restrict__ tmax, float* __restrict__ t,
                int* __restrict__ cnt) {
  __shared__ float pv[64][4][TOPK];
  const int rloc = threadIdx.x & 63, part = threadIdx.x >> 6;
  const int row = blockIdx.x * 64 + rloc;

  float vals[TOPK];
#pragma unroll
  for (int s = 0; s < TOPK; ++s) vals[s] = -INFINITY;
  const size_t base = (size_t)row * NQ + part * 64;
  for (int i = 0; i < 64; i += 4) {
    const f32x4 v = *(const f32x4*)&tmax[base + i];
#pragma unroll
    for (int e = 0; e < 4; ++e) tkv_insert<TOPK>(vals, v[e]);
  }
#pragma unroll
  for (int s = 0; s < TOPK; ++s) pv[rloc][part][s] = vals[s];
  __syncthreads();
  if (part == 0) {
    float v2[TOPK];
#pragma unroll
    for (int s = 0; s < TOPK; ++s) v2[s] = -INFINITY;
    for (int p = 0; p < 4; ++p)
#pragma unroll
      for (int s = 0; s < TOPK; ++s) tkv_insert<TOPK>(v2, pv[rloc][p][s]);
    t[row] = v2[0] - TMARGIN;   // v2[0] = 10th best
    cnt[row] = 0;
  }
}

// ---------------------------------------------------------------------------
// Screen pass B: identical GEMM; epilogue compares acc vs t[row] in registers
// and atomically appends passing columns (expected ~12-15 per row).
// ---------------------------------------------------------------------------
__global__ __launch_bounds__(256, 4)
void screen_collect(const unsigned short* __restrict__ Ehb,
                    const unsigned short* __restrict__ Etb,
                    const float* __restrict__ t, int* __restrict__ cnt,
                    int* __restrict__ cand) {
  __shared__ unsigned short As[BM * BK];   // 8 KB
  __shared__ unsigned short Bs[BN * BK];   // 8 KB

  const int tid = threadIdx.x;
  const int rowBase = blockIdx.x * BM;
  const int strip = blockIdx.y;
  const int w = tid >> 6, lane = tid & 63;
  const int q = lane >> 4, l15 = lane & 15;
  const int wr = (w & 1) * 64, wc = (w >> 1) * 64;

  const int c0 = tid, c1 = tid + 256;
  const int wb0 = __builtin_amdgcn_readfirstlane(tid & ~63);
  const int wb1 = wb0 + 256;
  const int ar0 = c0 >> 2, ac0 = (c0 & 3) * 8;
  const int ar1 = c1 >> 2, ac1 = (c1 & 3) * 8;

  // this thread's 16 row thresholds (rows fixed for the whole block)
  float tr[16];
#pragma unroll
  for (int i = 0; i < 4; ++i)
#pragma unroll
    for (int rg = 0; rg < 4; ++rg)
      tr[i * 4 + rg] = t[rowBase + wr + i * 16 + q * 4 + rg];

  for (int ct = 0; ct < SCOLS2; ct += BN) {
    const int colBase = strip * SCOLS2 + ct;
    f32x4 acc[4][4];
#pragma unroll
    for (int i = 0; i < 4; ++i)
#pragma unroll
      for (int j = 0; j < 4; ++j) acc[i][j] = (f32x4){0.f, 0.f, 0.f, 0.f};

    for (int kt = 0; kt < DIMK; kt += BK) {
      __syncthreads();
      gld16(Ehb + (size_t)(rowBase + ar0) * DIMK + kt + ac0, As + wb0 * 8);
      gld16(Ehb + (size_t)(rowBase + ar1) * DIMK + kt + ac1, As + wb1 * 8);
      gld16(Etb + (size_t)(colBase + ar0) * DIMK + kt + ac0, Bs + wb0 * 8);
      gld16(Etb + (size_t)(colBase + ar1) * DIMK + kt + ac1, Bs + wb1 * 8);
      __syncthreads();

      bf16x8 af[4], bf[4];
#pragma unroll
      for (int i = 0; i < 4; ++i)
        af[i] = *(const bf16x8*)&As[(wr + i * 16 + l15) * BK + q * 8];
#pragma unroll
      for (int j = 0; j < 4; ++j)
        bf[j] = *(const bf16x8*)&Bs[(wc + j * 16 + l15) * BK + q * 8];
#pragma unroll
      for (int i = 0; i < 4; ++i)
#pragma unroll
        for (int j = 0; j < 4; ++j)
          acc[i][j] = __builtin_amdgcn_mfma_f32_16x16x32_bf16(af[i], bf[j], acc[i][j], 0, 0, 0);
    }

    // Epilogue: register-space threshold compare + rare atomic append.
#pragma unroll
    for (int i = 0; i < 4; ++i)
#pragma unroll
      for (int rg = 0; rg < 4; ++rg) {
        const int row = rowBase + wr + i * 16 + q * 4 + rg;
        const float tt = tr[i * 4 + rg];
#pragma unroll
        for (int j = 0; j < 4; ++j) {
          const float v = acc[i][j][rg];
          if (v >= tt) {
            const int pos = atomicAdd(&cnt[row], 1);
            if (pos < CAP) cand[(size_t)row * CAP + pos] = colBase + wc + j * 16 + l15;
          }
        }
      }
  }
}

// ---------------------------------------------------------------------------
// Rescore: arithmetic BIT-IDENTICAL to round-1's logits path (sequential
// fmaf chain k=0..511, then *SCALE). Thread per (row, slot).
// ---------------------------------------------------------------------------
__global__ __launch_bounds__(256)
void rescore_chain(const float* __restrict__ Eh, const float* __restrict__ Et,
                   const int* __restrict__ cnt, const int* __restrict__ cand,
                   float* __restrict__ pscore) {
  const int idx = blockIdx.x * 256 + threadIdx.x;     // [0, NROWS*CAP)
  const int r = idx >> 6, c = idx & (CAP - 1);
  if (c >= cnt[r]) return;
  const int cc = cand[(size_t)r * CAP + c];
  const float* a = Eh + (size_t)r * DIMK;
  const float* b = Et + (size_t)cc * DIMK;
  float p = 0.f;
#pragma unroll 4
  for (int k = 0; k < DIMK; k += 4) {
    const float4 av = *(const float4*)&a[k];
    const float4 bv = *(const float4*)&b[k];
    p = fmaf(av.x, bv.x, p);
    p = fmaf(av.y, bv.y, p);
    p = fmaf(av.z, bv.z, p);
    p = fmaf(av.w, bv.w, p);
  }
  pscore[idx] = p * SCALE;
}

// ---------------------------------------------------------------------------
// Finalize: top-10 of exact scores, softmax, emit edge list.
// Output layout (all fp32): [src N*K][dst N*K][weight N*K].
// ---------------------------------------------------------------------------
__global__ __launch_bounds__(256)
void finalize(const float* __restrict__ pscore, const int* __restrict__ cnt,
              const int* __restrict__ cand, float* __restrict__ out) {
  const int r = blockIdx.x * 256 + threadIdx.x;
  const int n = min(cnt[r], CAP);
  float vals[TOPK]; int idxs[TOPK];
#pragma unroll
  for (int s = 0; s < TOPK; ++s) { vals[s] = -INFINITY; idxs[s] = 0; }
  for (int c = 0; c < n; ++c)
    tk_insert<TOPK>(vals, idxs, pscore[(size_t)r * CAP + c],
                    cand[(size_t)r * CAP + c]);

  const float m = vals[TOPK - 1];
  float w[TOPK]; float sum = 0.f;
#pragma unroll
  for (int j = 0; j < TOPK; ++j) { w[j] = expf(vals[TOPK - 1 - j] - m); sum += w[j]; }
  const float inv = 1.0f / sum;

  const size_t ro = (size_t)r * TOPK;
#pragma unroll
  for (int j = 0; j < TOPK; ++j) {
    out[ro + j] = (float)r;                                         // src
    out[(size_t)NROWS * TOPK + ro + j] = (float)idxs[TOPK - 1 - j]; // dst
    out[2 * (size_t)NROWS * TOPK + ro + j] = w[j] * inv;            // weight
  }
}

// ---------------------------------------------------------------------------
extern "C" void kernel_launch(void* const* d_in, const int* in_sizes, int n_in,
                              void* d_out, int out_size, void* d_ws, size_t ws_size,
                              hipStream_t stream) {
  const float* X  = (const float*)d_in[0];
  const float* Wh = (const float*)d_in[1];
  const float* bh = (const float*)d_in[2];
  const float* Wt = (const float*)d_in[3];
  const float* bt = (const float*)d_in[4];
  float* out = (float*)d_out;

  char* ws = (char*)d_ws;
  const size_t embB  = (size_t)NROWS * DIMK * sizeof(float);          // 16 MB
  const size_t embBH = (size_t)NROWS * DIMK * sizeof(unsigned short); //  8 MB
  const size_t tmaxB = (size_t)NROWS * NQ * sizeof(float);            //  8 MB
  const size_t tB    = (size_t)NROWS * sizeof(float);                 // 32 KB
  const size_t cntB  = (size_t)NROWS * sizeof(int);                   // 32 KB
  const size_t candB = (size_t)NROWS * CAP * sizeof(int);             //  2 MB
  float* Eh   = (float*)ws;
  float* Et   = (float*)(ws + embB);
  unsigned short* Ehb = (unsigned short*)(ws + 2 * embB);
  unsigned short* Etb = (unsigned short*)(ws + 2 * embB + embBH);
  float* tmax = (float*)(ws + 2 * embB + 2 * embBH);
  float* t    = (float*)(ws + 2 * embB + 2 * embBH + tmaxB);
  int*   cnt  = (int*)(ws + 2 * embB + 2 * embBH + tmaxB + tB);
  int*   cand = (int*)(ws + 2 * embB + 2 * embBH + tmaxB + tB + cntB);
  float* pscore = (float*)(ws + 2 * embB + 2 * embBH + tmaxB + tB + cntB + candB);
  // total ws use ~60 MB

  dim3 blk(NTHREADS);
  dim3 g1(NROWS / TM, (2 * DIMK) / TN);        // 128 x 16
  embed_gemm<<<g1, blk, 0, stream>>>(X, Wh, bh, Wt, bt, Eh, Et, Ehb, Etb);

  dim3 g2(NROWS / BM, NS2);                    // 64 x 16
  screen_max<<<g2, blk, 0, stream>>>(Ehb, Etb, tmax);

  row_thresh<<<NROWS / 64, blk, 0, stream>>>(tmax, t, cnt);

  screen_collect<<<g2, blk, 0, stream>>>(Ehb, Etb, t, cnt, cand);

  rescore_chain<<<(NROWS * CAP) / 256, blk, 0, stream>>>(Eh, Et, cnt, cand, pscore);

  finalize<<<NROWS / 256, blk, 0, stream>>>(pscore, cnt, cand, out);
}

// Round 5
// 450.067 us; speedup vs baseline: 4.1125x; 1.2395x over previous
//
#include <hip/hip_runtime.h>
#include <math.h>

// Problem constants (reference: N=8192, DIM=512, TOPK=10, all fp32)
#define NROWS 8192
#define DIMK  512
#define TOPK  10
#define SCALE 0.044194173824159223f   // fp32(512**-0.5)

// Phase-1 embed GEMM tiling (fp32 VALU)
#define TM 64
#define TN 64
#define TK 32
#define NTHREADS 256

// Screen GEMM tiling (bf16 MFMA)
#define BM 128
#define BN 128
#define BK 32
#define NS2 16                    // column strips for screen passes
#define SCOLS2 (NROWS / NS2)      // 512 cols per strip (4 tiles)
#define NQ 256                    // 32-col quarter-groups per row (8192/32)
#define CAP 64                    // max candidates per row
#define TMARGIN 2.0f              // safety margin: bf16-gemm noise (~0.65)
                                  // + bf16-storage rounding (~0.35) << 2.0

typedef __attribute__((ext_vector_type(8))) short bf16x8;   // 8 bf16 = 4 VGPRs
typedef __attribute__((ext_vector_type(4))) float f32x4;

// ---------------------------------------------------------------------------
// Register-resident sorted top-K (ascending; vals[0] = running min).
// ---------------------------------------------------------------------------
template <int K>
__device__ __forceinline__ void tk_insert(float (&vals)[K], int (&idxs)[K],
                                          float v, int idx) {
  if (v > vals[0]) {
    vals[0] = v; idxs[0] = idx;
#pragma unroll
    for (int s = 0; s < K - 1; ++s) {
      const bool sw = vals[s] > vals[s + 1];
      const float tv = vals[s]; const int ti = idxs[s];
      vals[s]     = sw ? vals[s + 1] : vals[s];
      idxs[s]     = sw ? idxs[s + 1] : idxs[s];
      vals[s + 1] = sw ? tv : vals[s + 1];
      idxs[s + 1] = sw ? ti : idxs[s + 1];
    }
  }
}

template <int K>
__device__ __forceinline__ void tkv_insert(float (&vals)[K], float v) {
  if (v > vals[0]) {
    vals[0] = v;
#pragma unroll
    for (int s = 0; s < K - 1; ++s) {
      const bool sw = vals[s] > vals[s + 1];
      const float tv = vals[s];
      vals[s]     = sw ? vals[s + 1] : vals[s];
      vals[s + 1] = sw ? tv : vals[s + 1];
    }
  }
}

__device__ __forceinline__ unsigned short f2bf(float f) {   // RNE fp32->bf16
  unsigned int u = __float_as_uint(f);
  u = (u + 0x7FFF + ((u >> 16) & 1)) >> 16;
  return (unsigned short)u;
}

// async global->LDS, 16B per lane; lds ptr must be wave-uniform base
__device__ __forceinline__ void gld16(const void* g, const void* lds) {
  __builtin_amdgcn_global_load_lds(
      (const __attribute__((address_space(1))) void*)g,
      (__attribute__((address_space(3))) void*)lds, 16, 0, 0);
}

// ---------------------------------------------------------------------------
// Phase 1: E = X @ W^T + b (fp32 exact, feeds rescore) + bf16 copies (screen).
// Arithmetic must stay bit-identical across rounds (rank near-ties).
// ---------------------------------------------------------------------------
__global__ __launch_bounds__(NTHREADS, 4)
void embed_gemm(const float* __restrict__ X,
                const float* __restrict__ Wh, const float* __restrict__ bh,
                const float* __restrict__ Wt, const float* __restrict__ bt,
                float* __restrict__ Eh, float* __restrict__ Et,
                unsigned short* __restrict__ Ehb, unsigned short* __restrict__ Etb) {
  __shared__ float As[TK][TM + 4];
  __shared__ float Bs[TK][TN + 4];

  const int tid = threadIdx.x;
  const int rowBase = blockIdx.x * TM;
  const int colBase = blockIdx.y * TN;          // 0..1023 over [Wh|Wt]
  const float* W  = (colBase < DIMK) ? Wh : Wt;
  const float* bb = (colBase < DIMK) ? bh : bt;
  float* Out            = (colBase < DIMK) ? Eh : Et;
  unsigned short* Outb  = (colBase < DIMK) ? Ehb : Etb;
  const int colOff = colBase & (DIMK - 1);

  const int tx = tid & 15, ty = tid >> 4;
  float acc[4][4];
#pragma unroll
  for (int r = 0; r < 4; ++r)
#pragma unroll
    for (int c = 0; c < 4; ++c) acc[r][c] = 0.f;

  for (int kt = 0; kt < DIMK; kt += TK) {
    __syncthreads();
#pragma unroll
    for (int u = 0; u < (TM * TK) / (4 * NTHREADS); ++u) {
      const int idx = tid + u * NTHREADS;
      const int r = idx >> 3;
      const int dc = idx & 7;
      const float4 av = *(const float4*)&X[(size_t)(rowBase + r) * DIMK + kt + dc * 4];
      As[dc * 4 + 0][r] = av.x; As[dc * 4 + 1][r] = av.y;
      As[dc * 4 + 2][r] = av.z; As[dc * 4 + 3][r] = av.w;
      const float4 bv = *(const float4*)&W[(size_t)(colOff + r) * DIMK + kt + dc * 4];
      Bs[dc * 4 + 0][r] = bv.x; Bs[dc * 4 + 1][r] = bv.y;
      Bs[dc * 4 + 2][r] = bv.z; Bs[dc * 4 + 3][r] = bv.w;
    }
    __syncthreads();
#pragma unroll
    for (int d4 = 0; d4 < TK; d4 += 4) {
#pragma unroll
      for (int q = 0; q < 4; ++q) {
        const float4 a = *(const float4*)&As[d4 + q][ty * 4];
        const float4 b = *(const float4*)&Bs[d4 + q][tx * 4];
        const float ar[4] = {a.x, a.y, a.z, a.w};
        const float br[4] = {b.x, b.y, b.z, b.w};
#pragma unroll
        for (int r = 0; r < 4; ++r)
#pragma unroll
          for (int c = 0; c < 4; ++c)
            acc[r][c] = fmaf(ar[r], br[c], acc[r][c]);
      }
    }
  }

  const float4 bv = *(const float4*)&bb[colOff + tx * 4];
  const float br[4] = {bv.x, bv.y, bv.z, bv.w};
#pragma unroll
  for (int r = 0; r < 4; ++r) {
    float4 o;
    o.x = acc[r][0] + br[0]; o.y = acc[r][1] + br[1];
    o.z = acc[r][2] + br[2]; o.w = acc[r][3] + br[3];
    const size_t off = (size_t)(rowBase + ty * 4 + r) * DIMK + colOff + tx * 4;
    *(float4*)&Out[off] = o;
    ushort4 ob;
    ob.x = f2bf(o.x); ob.y = f2bf(o.y); ob.z = f2bf(o.z); ob.w = f2bf(o.w);
    *(ushort4*)&Outb[off] = ob;
  }
}

// ---------------------------------------------------------------------------
// Screen pass (single GEMM): bf16 MFMA; epilogue dumps each 128x64 half-tile
// to LDS, then thread=(row, 32-col chunk) computes the chunk max (-> tmax)
// AND stores the 32 logits as bf16 to Sc. Lane pairs cover one 128-B line
// per row -> fully line-granular global writes.
// ---------------------------------------------------------------------------
__global__ __launch_bounds__(256, 3)
void screen_store(const unsigned short* __restrict__ Ehb,
                  const unsigned short* __restrict__ Etb,
                  float* __restrict__ tmax, unsigned short* __restrict__ Sc) {
  __shared__ unsigned short As[BM * BK];   // 8 KB
  __shared__ unsigned short Bs[BN * BK];   // 8 KB
  __shared__ float Cs[BM][68];             // 34.8 KB; rows 16B-aligned

  const int tid = threadIdx.x;
  const int rowBase = blockIdx.x * BM;
  const int strip = blockIdx.y;
  const int w = tid >> 6, lane = tid & 63;
  const int q = lane >> 4, l15 = lane & 15;
  const int wr = (w & 1) * 64, wc = (w >> 1) * 64;
  const int rr = tid >> 1, hq = tid & 1;   // epilogue: row / 32-col chunk

  const int c0 = tid, c1 = tid + 256;
  const int wb0 = __builtin_amdgcn_readfirstlane(tid & ~63);
  const int wb1 = wb0 + 256;
  const int ar0 = c0 >> 2, ac0 = (c0 & 3) * 8;
  const int ar1 = c1 >> 2, ac1 = (c1 & 3) * 8;

  for (int ct = 0; ct < SCOLS2; ct += BN) {
    const int colBase = strip * SCOLS2 + ct;
    const int tileG = colBase >> 7;          // global 128-col tile index
    f32x4 acc[4][4];
#pragma unroll
    for (int i = 0; i < 4; ++i)
#pragma unroll
      for (int j = 0; j < 4; ++j) acc[i][j] = (f32x4){0.f, 0.f, 0.f, 0.f};

    for (int kt = 0; kt < DIMK; kt += BK) {
      __syncthreads();
      gld16(Ehb + (size_t)(rowBase + ar0) * DIMK + kt + ac0, As + wb0 * 8);
      gld16(Ehb + (size_t)(rowBase + ar1) * DIMK + kt + ac1, As + wb1 * 8);
      gld16(Etb + (size_t)(colBase + ar0) * DIMK + kt + ac0, Bs + wb0 * 8);
      gld16(Etb + (size_t)(colBase + ar1) * DIMK + kt + ac1, Bs + wb1 * 8);
      __syncthreads();

      bf16x8 af[4], bf[4];
#pragma unroll
      for (int i = 0; i < 4; ++i)
        af[i] = *(const bf16x8*)&As[(wr + i * 16 + l15) * BK + q * 8];
#pragma unroll
      for (int j = 0; j < 4; ++j)
        bf[j] = *(const bf16x8*)&Bs[(wc + j * 16 + l15) * BK + q * 8];
#pragma unroll
      for (int i = 0; i < 4; ++i)
#pragma unroll
        for (int j = 0; j < 4; ++j)
          acc[i][j] = __builtin_amdgcn_mfma_f32_16x16x32_bf16(af[i], bf[j], acc[i][j], 0, 0, 0);
    }

    // Epilogue per 64-col half: dump -> (chunk max, bf16 store).
#pragma unroll
    for (int half = 0; half < 2; ++half) {
      if ((w >> 1) == half) {
#pragma unroll
        for (int i = 0; i < 4; ++i)
#pragma unroll
          for (int j = 0; j < 4; ++j)
#pragma unroll
            for (int rg = 0; rg < 4; ++rg)
              Cs[wr + i * 16 + q * 4 + rg][j * 16 + l15] = acc[i][j][rg];
      }
      __syncthreads();
      float m = -INFINITY;
      unsigned int pk[16];
#pragma unroll
      for (int k = 0; k < 8; ++k) {
        const f32x4 v = *(const f32x4*)&Cs[rr][hq * 32 + k * 4];
        m = fmaxf(m, fmaxf(fmaxf(v[0], v[1]), fmaxf(v[2], v[3])));
        pk[2 * k]     = (unsigned int)f2bf(v[0]) | ((unsigned int)f2bf(v[1]) << 16);
        pk[2 * k + 1] = (unsigned int)f2bf(v[2]) | ((unsigned int)f2bf(v[3]) << 16);
      }
      tmax[(size_t)(rowBase + rr) * NQ + tileG * 4 + half * 2 + hq] = m;
      unsigned int* dst = (unsigned int*)
          &Sc[(size_t)(rowBase + rr) * NROWS + colBase + half * 64 + hq * 32];
#pragma unroll
      for (int k = 0; k < 4; ++k)
        *(uint4*)&dst[k * 4] = make_uint4(pk[4*k], pk[4*k+1], pk[4*k+2], pk[4*k+3]);
      __syncthreads();   // readback done before next dump overwrites Cs
    }
  }
}

// ---------------------------------------------------------------------------
// Fallback pass A (ws too small for Sc): maxes only (round-4 path).
// ---------------------------------------------------------------------------
__global__ __launch_bounds__(256, 3)
void screen_max(const unsigned short* __restrict__ Ehb,
                const unsigned short* __restrict__ Etb,
                float* __restrict__ tmax) {
  __shared__ unsigned short As[BM * BK];
  __shared__ unsigned short Bs[BN * BK];
  __shared__ float Cs[BM][68];

  const int tid = threadIdx.x;
  const int rowBase = blockIdx.x * BM;
  const int strip = blockIdx.y;
  const int w = tid >> 6, lane = tid & 63;
  const int q = lane >> 4, l15 = lane & 15;
  const int wr = (w & 1) * 64, wc = (w >> 1) * 64;
  const int rr = tid & 127, hq = tid >> 7;

  const int c0 = tid, c1 = tid + 256;
  const int wb0 = __builtin_amdgcn_readfirstlane(tid & ~63);
  const int wb1 = wb0 + 256;
  const int ar0 = c0 >> 2, ac0 = (c0 & 3) * 8;
  const int ar1 = c1 >> 2, ac1 = (c1 & 3) * 8;

  for (int ct = 0; ct < SCOLS2; ct += BN) {
    const int colBase = strip * SCOLS2 + ct;
    const int tileG = colBase >> 7;
    f32x4 acc[4][4];
#pragma unroll
    for (int i = 0; i < 4; ++i)
#pragma unroll
      for (int j = 0; j < 4; ++j) acc[i][j] = (f32x4){0.f, 0.f, 0.f, 0.f};

    for (int kt = 0; kt < DIMK; kt += BK) {
      __syncthreads();
      gld16(Ehb + (size_t)(rowBase + ar0) * DIMK + kt + ac0, As + wb0 * 8);
      gld16(Ehb + (size_t)(rowBase + ar1) * DIMK + kt + ac1, As + wb1 * 8);
      gld16(Etb + (size_t)(colBase + ar0) * DIMK + kt + ac0, Bs + wb0 * 8);
      gld16(Etb + (size_t)(colBase + ar1) * DIMK + kt + ac1, Bs + wb1 * 8);
      __syncthreads();

      bf16x8 af[4], bf[4];
#pragma unroll
      for (int i = 0; i < 4; ++i)
        af[i] = *(const bf16x8*)&As[(wr + i * 16 + l15) * BK + q * 8];
#pragma unroll
      for (int j = 0; j < 4; ++j)
        bf[j] = *(const bf16x8*)&Bs[(wc + j * 16 + l15) * BK + q * 8];
#pragma unroll
      for (int i = 0; i < 4; ++i)
#pragma unroll
        for (int j = 0; j < 4; ++j)
          acc[i][j] = __builtin_amdgcn_mfma_f32_16x16x32_bf16(af[i], bf[j], acc[i][j], 0, 0, 0);
    }

#pragma unroll
    for (int half = 0; half < 2; ++half) {
      if ((w >> 1) == half) {
#pragma unroll
        for (int i = 0; i < 4; ++i)
#pragma unroll
          for (int j = 0; j < 4; ++j)
#pragma unroll
            for (int rg = 0; rg < 4; ++rg)
              Cs[wr + i * 16 + q * 4 + rg][j * 16 + l15] = acc[i][j][rg];
      }
      __syncthreads();
      float m = -INFINITY;
#pragma unroll
      for (int k = 0; k < 8; ++k) {
        const f32x4 v = *(const f32x4*)&Cs[rr][hq * 32 + k * 4];
        m = fmaxf(m, fmaxf(fmaxf(v[0], v[1]), fmaxf(v[2], v[3])));
      }
      tmax[(size_t)(rowBase + rr) * NQ + tileG * 4 + half * 2 + hq] = m;
      __syncthreads();
    }
  }
}

// ---------------------------------------------------------------------------
// Threshold: t[row] = (10th-best of 256 chunk maxes) - TMARGIN; zero cnt.
// ---------------------------------------------------------------------------
__global__ __launch_bounds__(256)
void row_thresh(const float* __restrict__ tmax, float* __restrict__ t,
                int* __restrict__ cnt) {
  __shared__ float pv[64][4][TOPK];
  const int rloc = threadIdx.x & 63, part = threadIdx.x >> 6;
  const int row = blockIdx.x * 64 + rloc;

  float vals[TOPK];
#pragma unroll
  for (int s = 0; s < TOPK; ++s) vals[s] = -INFINITY;
  const size_t base = (size_t)row * NQ + part * 64;
  for (int i = 0; i < 64; i += 4) {
    const f32x4 v = *(const f32x4*)&tmax[base + i];
#pragma unroll
    for (int e = 0; e < 4; ++e) tkv_insert<TOPK>(vals, v[e]);
  }
#pragma unroll
  for (int s = 0; s < TOPK; ++s) pv[rloc][part][s] = vals[s];
  __syncthreads();
  if (part == 0) {
    float v2[TOPK];
#pragma unroll
    for (int s = 0; s < TOPK; ++s) v2[s] = -INFINITY;
    for (int p = 0; p < 4; ++p)
#pragma unroll
      for (int s = 0; s < TOPK; ++s) tkv_insert<TOPK>(v2, pv[rloc][p][s]);
    t[row] = v2[0] - TMARGIN;   // v2[0] = 10th best
    cnt[row] = 0;
  }
}

// ---------------------------------------------------------------------------
// Collect (store path): memory-bound scan of stored bf16 logits vs t[row].
// One wave per row; lane reads 16 B (8 bf16) per iter, coalesced.
// ---------------------------------------------------------------------------
__global__ __launch_bounds__(256)
void collect_scan(const unsigned short* __restrict__ Sc,
                  const float* __restrict__ t, int* __restrict__ cnt,
                  int* __restrict__ cand) {
  const int lane = threadIdx.x & 63;
  const int r = blockIdx.x * 4 + (threadIdx.x >> 6);
  const float tt = t[r];
  const unsigned short* row = Sc + (size_t)r * NROWS;

#pragma unroll 1
  for (int it = 0; it < NROWS / 512; ++it) {
    const int c0 = it * 512 + lane * 8;
    const uint4 u = *(const uint4*)&row[c0];
    const unsigned int uu[4] = {u.x, u.y, u.z, u.w};
#pragma unroll
    for (int e = 0; e < 4; ++e) {
      const float lo = __uint_as_float(uu[e] << 16);
      const float hi = __uint_as_float(uu[e] & 0xFFFF0000u);
      if (lo >= tt) {
        const int p = atomicAdd(&cnt[r], 1);
        if (p < CAP) cand[(size_t)r * CAP + p] = c0 + 2 * e;
      }
      if (hi >= tt) {
        const int p = atomicAdd(&cnt[r], 1);
        if (p < CAP) cand[(size_t)r * CAP + p] = c0 + 2 * e + 1;
      }
    }
  }
}

// ---------------------------------------------------------------------------
// Fallback pass B (round-4): recompute GEMM, threshold-compare in registers.
// ---------------------------------------------------------------------------
__global__ __launch_bounds__(256, 4)
void screen_collect(const unsigned short* __restrict__ Ehb,
                    const unsigned short* __restrict__ Etb,
                    const float* __restrict__ t, int* __restrict__ cnt,
                    int* __restrict__ cand) {
  __shared__ unsigned short As[BM * BK];
  __shared__ unsigned short Bs[BN * BK];

  const int tid = threadIdx.x;
  const int rowBase = blockIdx.x * BM;
  const int strip = blockIdx.y;
  const int w = tid >> 6, lane = tid & 63;
  const int q = lane >> 4, l15 = lane & 15;
  const int wr = (w & 1) * 64, wc = (w >> 1) * 64;

  const int c0 = tid, c1 = tid + 256;
  const int wb0 = __builtin_amdgcn_readfirstlane(tid & ~63);
  const int wb1 = wb0 + 256;
  const int ar0 = c0 >> 2, ac0 = (c0 & 3) * 8;
  const int ar1 = c1 >> 2, ac1 = (c1 & 3) * 8;

  float tr[16];
#pragma unroll
  for (int i = 0; i < 4; ++i)
#pragma unroll
    for (int rg = 0; rg < 4; ++rg)
      tr[i * 4 + rg] = t[rowBase + wr + i * 16 + q * 4 + rg];

  for (int ct = 0; ct < SCOLS2; ct += BN) {
    const int colBase = strip * SCOLS2 + ct;
    f32x4 acc[4][4];
#pragma unroll
    for (int i = 0; i < 4; ++i)
#pragma unroll
      for (int j = 0; j < 4; ++j) acc[i][j] = (f32x4){0.f, 0.f, 0.f, 0.f};

    for (int kt = 0; kt < DIMK; kt += BK) {
      __syncthreads();
      gld16(Ehb + (size_t)(rowBase + ar0) * DIMK + kt + ac0, As + wb0 * 8);
      gld16(Ehb + (size_t)(rowBase + ar1) * DIMK + kt + ac1, As + wb1 * 8);
      gld16(Etb + (size_t)(colBase + ar0) * DIMK + kt + ac0, Bs + wb0 * 8);
      gld16(Etb + (size_t)(colBase + ar1) * DIMK + kt + ac1, Bs + wb1 * 8);
      __syncthreads();

      bf16x8 af[4], bf[4];
#pragma unroll
      for (int i = 0; i < 4; ++i)
        af[i] = *(const bf16x8*)&As[(wr + i * 16 + l15) * BK + q * 8];
#pragma unroll
      for (int j = 0; j < 4; ++j)
        bf[j] = *(const bf16x8*)&Bs[(wc + j * 16 + l15) * BK + q * 8];
#pragma unroll
      for (int i = 0; i < 4; ++i)
#pragma unroll
        for (int j = 0; j < 4; ++j)
          acc[i][j] = __builtin_amdgcn_mfma_f32_16x16x32_bf16(af[i], bf[j], acc[i][j], 0, 0, 0);
    }

#pragma unroll
    for (int i = 0; i < 4; ++i)
#pragma unroll
      for (int rg = 0; rg < 4; ++rg) {
        const int row = rowBase + wr + i * 16 + q * 4 + rg;
        const float tt = tr[i * 4 + rg];
#pragma unroll
        for (int j = 0; j < 4; ++j) {
          const float v = acc[i][j][rg];
          if (v >= tt) {
            const int pos = atomicAdd(&cnt[row], 1);
            if (pos < CAP) cand[(size_t)row * CAP + pos] = colBase + wc + j * 16 + l15;
          }
        }
      }
  }
}

// ---------------------------------------------------------------------------
// Rescore: arithmetic BIT-IDENTICAL to round-1's logits path (sequential
// fmaf chain k=0..511, then *SCALE). Thread per (row, slot).
// ---------------------------------------------------------------------------
__global__ __launch_bounds__(256)
void rescore_chain(const float* __restrict__ Eh, const float* __restrict__ Et,
                   const int* __restrict__ cnt, const int* __restrict__ cand,
                   float* __restrict__ pscore) {
  const int idx = blockIdx.x * 256 + threadIdx.x;     // [0, NROWS*CAP)
  const int r = idx >> 6, c = idx & (CAP - 1);
  if (c >= cnt[r]) return;
  const int cc = cand[(size_t)r * CAP + c];
  const float* a = Eh + (size_t)r * DIMK;
  const float* b = Et + (size_t)cc * DIMK;
  float p = 0.f;
#pragma unroll 4
  for (int k = 0; k < DIMK; k += 4) {
    const float4 av = *(const float4*)&a[k];
    const float4 bv = *(const float4*)&b[k];
    p = fmaf(av.x, bv.x, p);
    p = fmaf(av.y, bv.y, p);
    p = fmaf(av.z, bv.z, p);
    p = fmaf(av.w, bv.w, p);
  }
  pscore[idx] = p * SCALE;
}

// ---------------------------------------------------------------------------
// Finalize: top-10 of exact scores, softmax, emit edge list.
// Output layout (all fp32): [src N*K][dst N*K][weight N*K].
// ---------------------------------------------------------------------------
__global__ __launch_bounds__(256)
void finalize(const float* __restrict__ pscore, const int* __restrict__ cnt,
              const int* __restrict__ cand, float* __restrict__ out) {
  const int r = blockIdx.x * 256 + threadIdx.x;
  const int n = min(cnt[r], CAP);
  float vals[TOPK]; int idxs[TOPK];
#pragma unroll
  for (int s = 0; s < TOPK; ++s) { vals[s] = -INFINITY; idxs[s] = 0; }
  for (int c = 0; c < n; ++c)
    tk_insert<TOPK>(vals, idxs, pscore[(size_t)r * CAP + c],
                    cand[(size_t)r * CAP + c]);

  const float m = vals[TOPK - 1];
  float w[TOPK]; float sum = 0.f;
#pragma unroll
  for (int j = 0; j < TOPK; ++j) { w[j] = expf(vals[TOPK - 1 - j] - m); sum += w[j]; }
  const float inv = 1.0f / sum;

  const size_t ro = (size_t)r * TOPK;
#pragma unroll
  for (int j = 0; j < TOPK; ++j) {
    out[ro + j] = (float)r;                                         // src
    out[(size_t)NROWS * TOPK + ro + j] = (float)idxs[TOPK - 1 - j]; // dst
    out[2 * (size_t)NROWS * TOPK + ro + j] = w[j] * inv;            // weight
  }
}

// ---------------------------------------------------------------------------
extern "C" void kernel_launch(void* const* d_in, const int* in_sizes, int n_in,
                              void* d_out, int out_size, void* d_ws, size_t ws_size,
                              hipStream_t stream) {
  const float* X  = (const float*)d_in[0];
  const float* Wh = (const float*)d_in[1];
  const float* bh = (const float*)d_in[2];
  const float* Wt = (const float*)d_in[3];
  const float* bt = (const float*)d_in[4];
  float* out = (float*)d_out;

  char* ws = (char*)d_ws;
  const size_t embB  = (size_t)NROWS * DIMK * sizeof(float);          // 16 MB
  const size_t embBH = (size_t)NROWS * DIMK * sizeof(unsigned short); //  8 MB
  const size_t tmaxB = (size_t)NROWS * NQ * sizeof(float);            //  8 MB
  const size_t tB    = (size_t)NROWS * sizeof(float);                 // 32 KB
  const size_t cntB  = (size_t)NROWS * sizeof(int);                   // 32 KB
  const size_t candB = (size_t)NROWS * CAP * sizeof(int);             //  2 MB
  const size_t pscB  = (size_t)NROWS * CAP * sizeof(float);           //  2 MB
  const size_t scB   = (size_t)NROWS * NROWS * sizeof(unsigned short);// 128 MB
  float* Eh   = (float*)ws;
  float* Et   = (float*)(ws + embB);
  unsigned short* Ehb = (unsigned short*)(ws + 2 * embB);
  unsigned short* Etb = (unsigned short*)(ws + 2 * embB + embBH);
  float* tmax = (float*)(ws + 2 * embB + 2 * embBH);
  float* t    = (float*)(ws + 2 * embB + 2 * embBH + tmaxB);
  int*   cnt  = (int*)(ws + 2 * embB + 2 * embBH + tmaxB + tB);
  int*   cand = (int*)(ws + 2 * embB + 2 * embBH + tmaxB + tB + cntB);
  float* pscore = (float*)(ws + 2 * embB + 2 * embBH + tmaxB + tB + cntB + candB);
  unsigned short* Sc = (unsigned short*)
      (ws + 2 * embB + 2 * embBH + tmaxB + tB + cntB + candB + pscB);
  const size_t needB = 2 * embB + 2 * embBH + tmaxB + tB + cntB + candB + pscB + scB;

  dim3 blk(NTHREADS);
  dim3 g1(NROWS / TM, (2 * DIMK) / TN);        // 128 x 16
  embed_gemm<<<g1, blk, 0, stream>>>(X, Wh, bh, Wt, bt, Eh, Et, Ehb, Etb);

  dim3 g2(NROWS / BM, NS2);                    // 64 x 16
  if (ws_size >= needB) {
    // store path: single GEMM + memory-bound scan
    screen_store<<<g2, blk, 0, stream>>>(Ehb, Etb, tmax, Sc);
    row_thresh<<<NROWS / 64, blk, 0, stream>>>(tmax, t, cnt);
    collect_scan<<<NROWS / 4, blk, 0, stream>>>(Sc, t, cnt, cand);
  } else {
    // fallback (round-4): two GEMMs, no Sc buffer
    screen_max<<<g2, blk, 0, stream>>>(Ehb, Etb, tmax);
    row_thresh<<<NROWS / 64, blk, 0, stream>>>(tmax, t, cnt);
    screen_collect<<<g2, blk, 0, stream>>>(Ehb, Etb, t, cnt, cand);
  }

  rescore_chain<<<(NROWS * CAP) / 256, blk, 0, stream>>>(Eh, Et, cnt, cand, pscore);

  finalize<<<NROWS / 256, blk, 0, stream>>>(pscore, cnt, cand, out);
}